// Round 6
// baseline (310.373 us; speedup 1.0000x reference)
//
#include <hip/hip_runtime.h>
#include <hip/hip_bf16.h>

// GraphSage: 3x SAGEConv(mean) + linear head.
// r23: column-phase-split aggregate (zero-transform-cost locality).
//   - The 12.8MB feature table is L3-resident; aggregate traffic is L3->L2
//     bound with ~31% per-XCD L2 hit (4MB L2 vs 12.8MB working set).
//   - Aggregate now gathers each 256B row as TWO 128B half-row passes, with
//     the pass as the OUTER loop of an exactly-resident grid-stride kernel
//     (AGRID=2048 = 8 blocks/CU, all co-resident): every resident wave works
//     the same 6.4MB half of the table at the same time -> L2 hit ~62%,
//     L3 traffic ~141 -> ~78MB/layer. No sort, no atomics, no restructuring
//     (r20/r21 lesson: transform cost kills; this transform costs nothing).
//   - New lane map: eg=lane>>3 (8 edge groups), cl=lane&7 (8x16B chunks of a
//     half-row). ONE wave-load covers EIGHT half-rows (was 4 full rows) ->
//     gather instructions per edge halved. eg-reduce = shfl_xor 8,16,32.
// r22 carried: pack_w fused into packinit (9 launches); r19 GEMM double-
//   buffered A-prefetch (load-bearing); s_lo dropped; padded CSR (mult 8,
//   sentinel src=NN -> zeroed row); fixed-region bucket CSR build.
// r20 POST-MORTEM: per-node src sort cost +44us, gather gained 0.
// r21 POST-MORTEM: LDS-atomic scatter = 611us/dispatch (ds_add serialization).
// DO NOT RETRY: data-restructuring locality transforms; XCD affinity (r14/15);
//   fp8 gather (mean-of-16 e4m3 noise ~4.3e-3 > 3.85e-3 threshold).
// packed[] aliases s_hi (disjoint lifetime: consumed by bucket_csr pre-agg).

constexpr int NN = 50000;
constexpr int NE = 800000;
constexpr int NTILE = NN / 16;          // 3125 exact
constexpr int EPB = 4096;
constexpr int NBLK = (NE + EPB - 1) / EPB;   // 196
constexpr int NBUCK = 196;                   // ceil(NN/256)
constexpr int BCAP = 6144;   // packed bucket capacity (edges); mean 4096
constexpr int PCAP = 6144;   // padded perm bucket capacity; mean ~4992, mult of 8
constexpr int GGRID = 512;   // GEMM grid (2 blocks/CU)
constexpr int AGRID = 2048;  // aggregate grid: exactly-resident (8 blocks/CU)
constexpr int XBLK = (NN * 128 / 4 + 255) / 256;   // 6250 x-pack blocks

using bf16x8 = __attribute__((ext_vector_type(8))) short;
using f32x4  = __attribute__((ext_vector_type(4))) float;

__device__ __forceinline__ unsigned short bf16_rne(float f) {
    unsigned u = __float_as_uint(f);
    unsigned r = (u + 0x7FFFu + ((u >> 16) & 1u)) >> 16;
    return (unsigned short)r;
}
__device__ __forceinline__ float bf16_f(unsigned short h) {
    return __uint_as_float(((unsigned)h) << 16);
}
__device__ __forceinline__ unsigned pack_split(float v) {
    unsigned short hi = bf16_rne(v);
    float r = v - bf16_f(hi);
    unsigned short lo = bf16_rne(r);
    return (((unsigned)hi) << 16) | (unsigned)lo;
}

// --- pack x -> planar split bf16, init work, and all 3 weight packs -------
// blocks [0, XBLK): x-pack + out-bias + bcnt + sentinel row
// blocks [XBLK, XBLK+384): weight split-pack (layer = idx>>15)

__global__ __launch_bounds__(256) void k_packinit(const float* __restrict__ x,
        unsigned short* __restrict__ hhi, unsigned short* __restrict__ hlo,
        float* __restrict__ out, const float* __restrict__ bf,
        int* __restrict__ bcnt,
        const float* __restrict__ Wl0, const float* __restrict__ Wr0,
        const float* __restrict__ Wl1, const float* __restrict__ Wr1,
        const float* __restrict__ Wl2, const float* __restrict__ Wr2,
        unsigned short* __restrict__ whi, unsigned short* __restrict__ wlo) {
    if (blockIdx.x >= XBLK) {
        int gi = (blockIdx.x - XBLK) * 256 + threadIdx.x;  // 0..98303
        int layer = gi >> 15;
        int i = gi & 32767;
        const float* Wl = (layer == 0) ? Wl0 : (layer == 1) ? Wl1 : Wl2;
        const float* Wr = (layer == 0) ? Wr0 : (layer == 1) ? Wr1 : Wr2;
        int c = i >> 8;
        int k = i & 255;
        float v = (k < 128) ? Wl[c * 128 + k] : Wr[c * 128 + (k - 128)];
        unsigned short hi = bf16_rne(v);
        whi[gi] = hi;
        wlo[gi] = bf16_rne(v - bf16_f(hi));
        return;
    }
    int i = blockIdx.x * blockDim.x + threadIdx.x;
    constexpr int TOT = NN * 128 / 4;
    if (i < TOT) {
        float4 v = ((const float4*)x)[i];
        unsigned p0 = pack_split(v.x), p1 = pack_split(v.y);
        unsigned p2 = pack_split(v.z), p3 = pack_split(v.w);
        uint2 hi, lo;
        hi.x = (p0 >> 16) | (p1 & 0xFFFF0000u);
        hi.y = (p2 >> 16) | (p3 & 0xFFFF0000u);
        lo.x = (p0 & 0xFFFFu) | (p1 << 16);
        lo.y = (p2 & 0xFFFFu) | (p3 << 16);
        ((uint2*)hhi)[i] = hi;
        ((uint2*)hlo)[i] = lo;
    }
    if (i < NN) out[i] = bf[0];
    if (i < 256) bcnt[i] = 0;
    if (i < 128) hhi[(size_t)NN * 128 + i] = 0;   // sentinel row for pad edges
}

// ---------------- CSR build: one-pass bucket scatter ----------------

__global__ __launch_bounds__(256) void k_build_buckets(const int* __restrict__ ei,
        int* __restrict__ bcnt, unsigned* __restrict__ packed) {
    __shared__ unsigned stage[EPB];   // 16KB
    __shared__ int h[256];
    __shared__ int cur[256];
    int t = threadIdx.x;
    h[t] = 0;
    __syncthreads();
    int e0 = blockIdx.x * EPB;
    int e1 = e0 + EPB; if (e1 > NE) e1 = NE;
    for (int e = e0 + t; e < e1; e += 256) {
        int s = ei[e];
        int d = ei[NE + e];
        stage[e - e0] = ((unsigned)d << 16) | (unsigned)s;
        atomicAdd(&h[d >> 8], 1);
    }
    __syncthreads();
    if (t < NBUCK) cur[t] = t * BCAP + atomicAdd(&bcnt[t], h[t]);
    __syncthreads();
    for (int e = e0 + t; e < e1; e += 256) {
        unsigned r = stage[e - e0];
        int pos = atomicAdd(&cur[r >> 24], 1);   // bucket = d>>8 = r>>24
        packed[pos] = r;
    }
}

// Per bucket: LDS counting sort by (d&255) with per-node padding to mult of 8;
// pad slots filled with sentinel NN. row_start points into b*PCAP region.
__global__ __launch_bounds__(256) void k_bucket_csr(const unsigned* __restrict__ packed,
        const int* __restrict__ bcnt, unsigned short* __restrict__ perm,
        int* __restrict__ cnt, int* __restrict__ row_start) {
    __shared__ unsigned recs[BCAP];       // 24KB
    __shared__ unsigned short outs[PCAP]; // 12KB
    __shared__ int cntL[256];
    __shared__ int ws[4];
    __shared__ int totS;
    int b = blockIdx.x;
    int m = bcnt[b];
    if (m > BCAP) m = BCAP;
    int t = threadIdx.x;
    cntL[t] = 0;
    __syncthreads();
    int lo = b * BCAP;
    for (int i = t; i < m; i += 256) {
        unsigned r = packed[lo + i];
        recs[i] = r;
        atomicAdd(&cntL[(r >> 16) & 255], 1);
    }
    __syncthreads();
    int lane = t & 63, wave = t >> 6;
    int orig = cntL[t];
    int pc = (orig + 7) & ~7;            // padded per-node degree
    int v = pc;
    for (int o = 1; o < 64; o <<= 1) { int u = __shfl_up(v, o); if (lane >= o) v += u; }
    if (lane == 63) ws[wave] = v;
    __syncthreads();
    int off = 0;
    for (int w = 0; w < wave; ++w) off += ws[w];
    int st = v + off - pc;               // exclusive scan of padded degrees
    int node = b * 256 + t;
    if (node < NN) { cnt[node] = orig; row_start[node] = b * PCAP + st; }
    if (t == 255) totS = st + pc;
    __syncthreads();
    cntL[t] = st;
    __syncthreads();
    for (int i = t; i < m; i += 256) {
        unsigned r = recs[i];
        int pos = atomicAdd(&cntL[(r >> 16) & 255], 1);
        outs[pos] = (unsigned short)(r & 0xFFFFu);
    }
    // pad fill: disjoint from scatter's target region, no barrier needed
    for (int i = st + orig; i < st + pc; ++i) outs[i] = (unsigned short)NN;
    __syncthreads();
    int totp = totS;
    for (int i = t; i < totp; i += 256)
        perm[b * PCAP + i] = outs[i];
}

// ---------------- aggregate: column-phase-split gather mean ----------------
// Exactly-resident grid-stride (AGRID=2048 = 8 blocks/CU). Outer loop = the
// column half p: all resident waves gather from the same 6.4MB half of the
// table concurrently -> per-XCD L2 hit ~62% (vs 31% whole-table).
// lane = (eg = lane>>3: 8 edge groups, cl = lane&7: 16B chunk of half-row).
// One uint4 wave-load covers EIGHT 128B half-rows. eg-reduce: xor 8,16,32.
__global__ __launch_bounds__(256) void k_aggregate(const unsigned short* __restrict__ hhi,
        const int* __restrict__ row_start, const int* __restrict__ cnt,
        const unsigned short* __restrict__ perm,
        unsigned short* __restrict__ shi) {
    int wave = __builtin_amdgcn_readfirstlane(threadIdx.x >> 6);
    int lane = threadIdx.x & 63;
    int eg = lane >> 3;                       // edge group 0..7
    int cl = lane & 7;                        // 16B col chunk within half-row
    int hsh = (eg & 1) << 4;                  // ushort half within u32
    int wsel = eg >> 1;                       // u32 component of perm uint4
    const char* base = (const char*)hhi;      // row stride 256B
#define PICK(P) ((((wsel & 2) ? ((wsel & 1) ? (P).w : (P).z) \
                              : ((wsel & 1) ? (P).y : (P).x)) >> hsh) & 0xFFFFu)
#define ACC8(q) { a0 += __uint_as_float((q).x << 16); a1 += __uint_as_float((q).x & 0xFFFF0000u); \
                  a2 += __uint_as_float((q).y << 16); a3 += __uint_as_float((q).y & 0xFFFF0000u); \
                  a4 += __uint_as_float((q).z << 16); a5 += __uint_as_float((q).z & 0xFFFF0000u); \
                  a6 += __uint_as_float((q).w << 16); a7 += __uint_as_float((q).w & 0xFFFF0000u); }
    for (int p = 0; p < 2; ++p) {
        int cbyte = p * 128 + cl * 16;
#define GATH(w) (*(const uint4*)(base + ((size_t)(w) << 8) + cbyte))
        for (int node = blockIdx.x * 4 + wave; node < NN; node += AGRID * 4) {
            int deg = cnt[node];
            int start = row_start[node];      // multiple of 8 -> 16B aligned
            float a0=0.f,a1=0.f,a2=0.f,a3=0.f,a4=0.f,a5=0.f,a6=0.f,a7=0.f;
            int nIter = ((deg + 7) & ~7) >> 3;        // 8 edges per iter
            const uint4* pp = (const uint4*)(perm + start);
            int j = 0;
            for (; j + 2 <= nIter; j += 2) {          // 16 edges: 2 gathers
                uint4 P0 = pp[j], P1 = pp[j + 1];
                unsigned w0 = PICK(P0);
                unsigned w1 = PICK(P1);
                uint4 q0 = GATH(w0);
                uint4 q1 = GATH(w1);
                ACC8(q0); ACC8(q1);
            }
            if (j < nIter) {                          // one 8-edge step
                uint4 P0 = pp[j];
                unsigned w0 = PICK(P0);
                uint4 q0 = GATH(w0);
                ACC8(q0);
            }
            // reduce across 8 edge groups (eg = lane bits 3..5)
            a0 += __shfl_xor(a0, 8);  a1 += __shfl_xor(a1, 8);
            a2 += __shfl_xor(a2, 8);  a3 += __shfl_xor(a3, 8);
            a4 += __shfl_xor(a4, 8);  a5 += __shfl_xor(a5, 8);
            a6 += __shfl_xor(a6, 8);  a7 += __shfl_xor(a7, 8);
            a0 += __shfl_xor(a0, 16); a1 += __shfl_xor(a1, 16);
            a2 += __shfl_xor(a2, 16); a3 += __shfl_xor(a3, 16);
            a4 += __shfl_xor(a4, 16); a5 += __shfl_xor(a5, 16);
            a6 += __shfl_xor(a6, 16); a7 += __shfl_xor(a7, 16);
            a0 += __shfl_xor(a0, 32); a1 += __shfl_xor(a1, 32);
            a2 += __shfl_xor(a2, 32); a3 += __shfl_xor(a3, 32);
            a4 += __shfl_xor(a4, 32); a5 += __shfl_xor(a5, 32);
            a6 += __shfl_xor(a6, 32); a7 += __shfl_xor(a7, 32);
            float inv = 1.0f / (float)(deg > 1 ? deg : 1);
            if (eg == 0) {                    // lanes 0..7 = cl 0..7
                uint4 o;
                o.x = (unsigned)bf16_rne(a0 * inv) | ((unsigned)bf16_rne(a1 * inv) << 16);
                o.y = (unsigned)bf16_rne(a2 * inv) | ((unsigned)bf16_rne(a3 * inv) << 16);
                o.z = (unsigned)bf16_rne(a4 * inv) | ((unsigned)bf16_rne(a5 * inv) << 16);
                o.w = (unsigned)bf16_rne(a6 * inv) | ((unsigned)bf16_rne(a7 * inv) << 16);
                ((uint4*)shi)[(size_t)node * 16 + p * 8 + cl] = o;
            }
        }
#undef GATH
    }
#undef ACC8
#undef PICK
}

// ---------------- weight-stationary MFMA GEMM (pipelined grid-stride) ------
// out[n][c] = relu( bias[c] + sum_k [S|H][n][k] W[c][k] )
// A = {s_hi (mean, bf16), h_hi+h_lo (x, split)}. 12 dwordx4 A loads/tile,
// double-buffered across the grid-stride loop (prefetch t+512 before MFMA(t)).
#define GEMM_PROLOG \
    int wave = __builtin_amdgcn_readfirstlane(threadIdx.x >> 6); \
    int lane = threadIdx.x & 63; \
    int row = lane & 15; \
    int kb = lane >> 4; \
    int ct0 = wave * 2; \
    bf16x8 bh[2][8], bl[2][8]; \
    _Pragma("unroll") \
    for (int c = 0; c < 2; ++c) \
        _Pragma("unroll") \
        for (int kc = 0; kc < 8; ++kc) { \
            size_t widx = (size_t)((ct0 + c) * 16 + row) * 256 + kc * 32 + kb * 8; \
            bh[c][kc] = *(const bf16x8*)(Whi + widx); \
            bl[c][kc] = *(const bf16x8*)(Wlo + widx); \
        } \
    float b0 = bias[ct0 * 16 + row]; \
    float b1 = bias[ct0 * 16 + 16 + row];

#define LOADT(AS, AH, AL, t) { \
        size_t rb = (size_t)((t) * 16 + row) * 128 + kb * 8; \
        _Pragma("unroll") \
        for (int kc = 0; kc < 4; ++kc) { \
            AS[kc] = *(const bf16x8*)(Ash + rb + kc * 32); \
            AH[kc] = *(const bf16x8*)(Ahh + rb + kc * 32); \
            AL[kc] = *(const bf16x8*)(Ahl + rb + kc * 32); \
        } }

#define MFMA40(AS, AH, AL) \
        f32x4 acc0 = {0.f, 0.f, 0.f, 0.f}; \
        f32x4 acc1 = {0.f, 0.f, 0.f, 0.f}; \
        _Pragma("unroll") \
        for (int kc = 0; kc < 4; ++kc) { \
            acc0 = __builtin_amdgcn_mfma_f32_16x16x32_bf16(AS[kc], bh[0][kc], acc0, 0, 0, 0); \
            acc0 = __builtin_amdgcn_mfma_f32_16x16x32_bf16(AS[kc], bl[0][kc], acc0, 0, 0, 0); \
            acc1 = __builtin_amdgcn_mfma_f32_16x16x32_bf16(AS[kc], bh[1][kc], acc1, 0, 0, 0); \
            acc1 = __builtin_amdgcn_mfma_f32_16x16x32_bf16(AS[kc], bl[1][kc], acc1, 0, 0, 0); \
        } \
        _Pragma("unroll") \
        for (int kc = 0; kc < 4; ++kc) { \
            acc0 = __builtin_amdgcn_mfma_f32_16x16x32_bf16(AH[kc], bh[0][4 + kc], acc0, 0, 0, 0); \
            acc0 = __builtin_amdgcn_mfma_f32_16x16x32_bf16(AL[kc], bh[0][4 + kc], acc0, 0, 0, 0); \
            acc0 = __builtin_amdgcn_mfma_f32_16x16x32_bf16(AH[kc], bl[0][4 + kc], acc0, 0, 0, 0); \
            acc1 = __builtin_amdgcn_mfma_f32_16x16x32_bf16(AH[kc], bh[1][4 + kc], acc1, 0, 0, 0); \
            acc1 = __builtin_amdgcn_mfma_f32_16x16x32_bf16(AL[kc], bh[1][4 + kc], acc1, 0, 0, 0); \
            acc1 = __builtin_amdgcn_mfma_f32_16x16x32_bf16(AH[kc], bl[1][4 + kc], acc1, 0, 0, 0); \
        }

__global__ __launch_bounds__(256, 2) void k_gemm_ws(
        const unsigned short* __restrict__ Ash,
        const unsigned short* __restrict__ Ahh, const unsigned short* __restrict__ Ahl,
        const unsigned short* __restrict__ Whi, const unsigned short* __restrict__ Wlo,
        const float* __restrict__ bias,
        unsigned short* __restrict__ Ohi, unsigned short* __restrict__ Olo) {
    GEMM_PROLOG
#define STEP(AS, AH, AL, t) { \
        MFMA40(AS, AH, AL) \
        __syncthreads();   /* all waves' reads of tile t precede its writes */ \
        int cb0 = ct0 * 16 + row; \
        _Pragma("unroll") \
        for (int r = 0; r < 4; ++r) { \
            size_t ro = (size_t)((t) * 16 + kb * 4 + r) * 128; \
            unsigned p0 = pack_split(fmaxf(acc0[r] + b0, 0.f)); \
            unsigned p1 = pack_split(fmaxf(acc1[r] + b1, 0.f)); \
            Ohi[ro + cb0]      = (unsigned short)(p0 >> 16); \
            Olo[ro + cb0]      = (unsigned short)(p0 & 0xFFFFu); \
            Ohi[ro + cb0 + 16] = (unsigned short)(p1 >> 16); \
            Olo[ro + cb0 + 16] = (unsigned short)(p1 & 0xFFFFu); \
        } }
    bf16x8 sA[4], hA[4], lA[4], sB[4], hB[4], lB[4];
    int t = blockIdx.x;
    LOADT(sA, hA, lA, t)
    int tn = t + GGRID;
    for (;;) {
        if (tn < NTILE) LOADT(sB, hB, lB, tn)
        STEP(sA, hA, lA, t)
        if (tn >= NTILE) break;
        t = tn; tn += GGRID;
        if (tn < NTILE) LOADT(sA, hA, lA, tn)
        STEP(sB, hB, lB, t)
        if (tn >= NTILE) break;
        t = tn; tn += GGRID;
    }
#undef STEP
}

// layer-2 variant: head fused — out[n] += sum_c relu(h3[n][c]) * Wf[c]
__global__ __launch_bounds__(256, 2) void k_gemm_head(
        const unsigned short* __restrict__ Ash,
        const unsigned short* __restrict__ Ahh, const unsigned short* __restrict__ Ahl,
        const unsigned short* __restrict__ Whi, const unsigned short* __restrict__ Wlo,
        const float* __restrict__ bias, const float* __restrict__ Wf,
        float* __restrict__ out) {
    GEMM_PROLOG
    float w0 = Wf[ct0 * 16 + row];
    float w1 = Wf[ct0 * 16 + 16 + row];
#define HSTEP(AS, AH, AL, t) { \
        MFMA40(AS, AH, AL) \
        float part[4]; \
        _Pragma("unroll") \
        for (int r = 0; r < 4; ++r) \
            part[r] = fmaxf(acc0[r] + b0, 0.f) * w0 + fmaxf(acc1[r] + b1, 0.f) * w1; \
        _Pragma("unroll") \
        for (int o = 1; o < 16; o <<= 1) { \
            _Pragma("unroll") \
            for (int r = 0; r < 4; ++r) part[r] += __shfl_xor(part[r], o); \
        } \
        if (row == 0) { \
            _Pragma("unroll") \
            for (int r = 0; r < 4; ++r) atomicAdd(&out[(t) * 16 + kb * 4 + r], part[r]); \
        } }
    bf16x8 sA[4], hA[4], lA[4], sB[4], hB[4], lB[4];
    int t = blockIdx.x;
    LOADT(sA, hA, lA, t)
    int tn = t + GGRID;
    for (;;) {
        if (tn < NTILE) LOADT(sB, hB, lB, tn)
        HSTEP(sA, hA, lA, t)
        if (tn >= NTILE) break;
        t = tn; tn += GGRID;
        if (tn < NTILE) LOADT(sA, hA, lA, tn)
        HSTEP(sB, hB, lB, t)
        if (tn >= NTILE) break;
        t = tn; tn += GGRID;
    }
#undef HSTEP
}

extern "C" void kernel_launch(void* const* d_in, const int* in_sizes, int n_in,
                              void* d_out, int out_size, void* d_ws, size_t ws_size,
                              hipStream_t stream) {
    const float* x   = (const float*)d_in[0];
    const int*   ei  = (const int*)d_in[1];
    const float* Wl0 = (const float*)d_in[2];
    const float* bl0 = (const float*)d_in[3];
    const float* Wr0 = (const float*)d_in[4];
    const float* Wl1 = (const float*)d_in[5];
    const float* bl1 = (const float*)d_in[6];
    const float* Wr1 = (const float*)d_in[7];
    const float* Wl2 = (const float*)d_in[8];
    const float* bl2 = (const float*)d_in[9];
    const float* Wr2 = (const float*)d_in[10];
    const float* Wf  = (const float*)d_in[11];
    const float* bf  = (const float*)d_in[12];
    float* out = (float*)d_out;

    char* p = (char*)d_ws;
    auto alloc = [&](size_t n) { void* r = (void*)p; p += (n + 255) & ~(size_t)255; return r; };
    int*            bcnt      = (int*)alloc(256 * 4);
    int*            cnt       = (int*)alloc((size_t)NN * 4);
    int*            row_start = (int*)alloc((size_t)NN * 4);
    unsigned short* perm      = (unsigned short*)alloc((size_t)NBUCK * PCAP * 2);
    unsigned short* s_hi      = (unsigned short*)alloc((size_t)(NN + 1) * 128 * 2);
    unsigned short* h_hi      = (unsigned short*)alloc((size_t)(NN + 1) * 128 * 2);
    unsigned short* h_lo      = (unsigned short*)alloc((size_t)(NN + 1) * 128 * 2);
    unsigned short* whi       = (unsigned short*)alloc((size_t)3 * 128 * 256 * 2);
    unsigned short* wlo       = (unsigned short*)alloc((size_t)3 * 128 * 256 * 2);
    unsigned*       packed    = (unsigned*)s_hi;  // 4.8MB < 12.8MB; consumed
                                                  // by bucket_csr before agg

    dim3 b256(256);
    // pack x + weights + all init (out bias, bcnt, sentinel) — precedes build
    k_packinit<<<dim3(XBLK + 384), b256, 0, stream>>>(
        x, h_hi, h_lo, out, bf, bcnt,
        Wl0, Wr0, Wl1, Wr1, Wl2, Wr2, whi, wlo);
    // CSR build: 2 kernels
    k_build_buckets<<<dim3(NBLK), b256, 0, stream>>>(ei, bcnt, packed);
    k_bucket_csr<<<dim3(NBUCK), b256, 0, stream>>>(packed, bcnt, perm, cnt, row_start);

    dim3 gAgg(AGRID);           // exactly-resident grid-stride, phase-aligned
    dim3 gGemm(GGRID);          // 2 blocks/CU; grid-stride over 3125 tiles

    // layer 0
    k_aggregate<<<gAgg, b256, 0, stream>>>(h_hi, row_start, cnt, perm, s_hi);
    k_gemm_ws<<<gGemm, b256, 0, stream>>>(s_hi, h_hi, h_lo,
                                          whi + 0 * 32768, wlo + 0 * 32768, bl0, h_hi, h_lo);
    // layer 1 (in place)
    k_aggregate<<<gAgg, b256, 0, stream>>>(h_hi, row_start, cnt, perm, s_hi);
    k_gemm_ws<<<gGemm, b256, 0, stream>>>(s_hi, h_hi, h_lo,
                                          whi + 1 * 32768, wlo + 1 * 32768, bl1, h_hi, h_lo);
    // layer 2 + fused head
    k_aggregate<<<gAgg, b256, 0, stream>>>(h_hi, row_start, cnt, perm, s_hi);
    k_gemm_head<<<gGemm, b256, 0, stream>>>(s_hi, h_hi, h_lo,
                                            whi + 2 * 32768, wlo + 2 * 32768, bl2, Wf, out);
}

// Round 7
// 284.647 us; speedup vs baseline: 1.0904x; 1.0904x over previous
//
#include <hip/hip_runtime.h>
#include <hip/hip_bf16.h>

// GraphSage: 3x SAGEConv(mean) + linear head.
// r24: REVERT to r22 exactly (best measured: 283.9us). No new experiments.
//   - r23 POST-MORTEM: column-phase-split aggregate +26us. Halved gather MLP
//     (2 outstanding uint4 vs 4), doubled perm walks; L2-hit gain never
//     materialized (half-rows occupy the same scattered cache lines).
//   - r20 POST-MORTEM: per-node src sort cost +44us, gather gained 0.
//   - r21 POST-MORTEM: LDS-atomic scatter = 611us/dispatch (ds_add
//     serialization + bank contention).
//   - STRUCTURAL CEILING (3 failed mechanisms, do not retry): aggregate is
//     BANDWIDTH-bound on the L3 random-256B-granule stream at ~5 TB/s
//     (Little's law: ~5-8 outstanding wave-gathers/CU suffice; we have 100+,
//     so not latency-bound). Converting random->coherent always cost more
//     than the ~20% random-granule penalty it recovers.
// Structure (r22): aggregate gathers ONLY the hi plane; CSR rows padded to
//   mult of 8 with sentinel src=NN (zeroed row, L1-resident) -> no tail
//   loops; uint4 gather: lane=(edge group, col chunk), one wave-load = FOUR
//   256B rows; GEMM double-buffers the A-tile across the grid-stride loop
//   (prefetch t+512 before MFMA(t); in-place safe: tile t+512's rows are
//   written only by this same block, later); s_lo plane dropped (mean is
//   bf16-precision anyway); pack_w fused into packinit (9 launches).
// CSR build: fixed bucket regions + LDS hist + one atomicAdd range reserve.
// Structure: SEPARATE aggregate and GEMM (r12 fusion starved the gather).
// XCD affinity NOT controllable from HIP (r14/r15) — do not retry.
// fp8 gather REJECTED: mean-of-16 e4m3 noise ~4.3e-3 > 3.85e-3 threshold.
// packed[] aliases s_hi (disjoint lifetime: consumed by bucket_csr pre-agg).

constexpr int NN = 50000;
constexpr int NE = 800000;
constexpr int NTILE = NN / 16;          // 3125 exact
constexpr int EPB = 4096;
constexpr int NBLK = (NE + EPB - 1) / EPB;   // 196
constexpr int NBUCK = 196;                   // ceil(NN/256)
constexpr int BCAP = 6144;   // packed bucket capacity (edges); mean 4096
constexpr int PCAP = 6144;   // padded perm bucket capacity; mean ~4992, mult of 8
constexpr int GGRID = 512;   // GEMM grid (2 blocks/CU)
constexpr int XBLK = (NN * 128 / 4 + 255) / 256;   // 6250 x-pack blocks

using bf16x8 = __attribute__((ext_vector_type(8))) short;
using f32x4  = __attribute__((ext_vector_type(4))) float;

__device__ __forceinline__ unsigned short bf16_rne(float f) {
    unsigned u = __float_as_uint(f);
    unsigned r = (u + 0x7FFFu + ((u >> 16) & 1u)) >> 16;
    return (unsigned short)r;
}
__device__ __forceinline__ float bf16_f(unsigned short h) {
    return __uint_as_float(((unsigned)h) << 16);
}
__device__ __forceinline__ unsigned pack_split(float v) {
    unsigned short hi = bf16_rne(v);
    float r = v - bf16_f(hi);
    unsigned short lo = bf16_rne(r);
    return (((unsigned)hi) << 16) | (unsigned)lo;
}

// --- pack x -> planar split bf16, init work, and all 3 weight packs -------
// blocks [0, XBLK): x-pack + out-bias + bcnt + sentinel row
// blocks [XBLK, XBLK+384): weight split-pack (layer = idx>>15)

__global__ __launch_bounds__(256) void k_packinit(const float* __restrict__ x,
        unsigned short* __restrict__ hhi, unsigned short* __restrict__ hlo,
        float* __restrict__ out, const float* __restrict__ bf,
        int* __restrict__ bcnt,
        const float* __restrict__ Wl0, const float* __restrict__ Wr0,
        const float* __restrict__ Wl1, const float* __restrict__ Wr1,
        const float* __restrict__ Wl2, const float* __restrict__ Wr2,
        unsigned short* __restrict__ whi, unsigned short* __restrict__ wlo) {
    if (blockIdx.x >= XBLK) {
        int gi = (blockIdx.x - XBLK) * 256 + threadIdx.x;  // 0..98303
        int layer = gi >> 15;
        int i = gi & 32767;
        const float* Wl = (layer == 0) ? Wl0 : (layer == 1) ? Wl1 : Wl2;
        const float* Wr = (layer == 0) ? Wr0 : (layer == 1) ? Wr1 : Wr2;
        int c = i >> 8;
        int k = i & 255;
        float v = (k < 128) ? Wl[c * 128 + k] : Wr[c * 128 + (k - 128)];
        unsigned short hi = bf16_rne(v);
        whi[gi] = hi;
        wlo[gi] = bf16_rne(v - bf16_f(hi));
        return;
    }
    int i = blockIdx.x * blockDim.x + threadIdx.x;
    constexpr int TOT = NN * 128 / 4;
    if (i < TOT) {
        float4 v = ((const float4*)x)[i];
        unsigned p0 = pack_split(v.x), p1 = pack_split(v.y);
        unsigned p2 = pack_split(v.z), p3 = pack_split(v.w);
        uint2 hi, lo;
        hi.x = (p0 >> 16) | (p1 & 0xFFFF0000u);
        hi.y = (p2 >> 16) | (p3 & 0xFFFF0000u);
        lo.x = (p0 & 0xFFFFu) | (p1 << 16);
        lo.y = (p2 & 0xFFFFu) | (p3 << 16);
        ((uint2*)hhi)[i] = hi;
        ((uint2*)hlo)[i] = lo;
    }
    if (i < NN) out[i] = bf[0];
    if (i < 256) bcnt[i] = 0;
    if (i < 128) hhi[(size_t)NN * 128 + i] = 0;   // sentinel row for pad edges
}

// ---------------- CSR build: one-pass bucket scatter ----------------

__global__ __launch_bounds__(256) void k_build_buckets(const int* __restrict__ ei,
        int* __restrict__ bcnt, unsigned* __restrict__ packed) {
    __shared__ unsigned stage[EPB];   // 16KB
    __shared__ int h[256];
    __shared__ int cur[256];
    int t = threadIdx.x;
    h[t] = 0;
    __syncthreads();
    int e0 = blockIdx.x * EPB;
    int e1 = e0 + EPB; if (e1 > NE) e1 = NE;
    for (int e = e0 + t; e < e1; e += 256) {
        int s = ei[e];
        int d = ei[NE + e];
        stage[e - e0] = ((unsigned)d << 16) | (unsigned)s;
        atomicAdd(&h[d >> 8], 1);
    }
    __syncthreads();
    if (t < NBUCK) cur[t] = t * BCAP + atomicAdd(&bcnt[t], h[t]);
    __syncthreads();
    for (int e = e0 + t; e < e1; e += 256) {
        unsigned r = stage[e - e0];
        int pos = atomicAdd(&cur[r >> 24], 1);   // bucket = d>>8 = r>>24
        packed[pos] = r;
    }
}

// Per bucket: LDS counting sort by (d&255) with per-node padding to mult of 8;
// pad slots filled with sentinel NN. row_start points into b*PCAP region.
__global__ __launch_bounds__(256) void k_bucket_csr(const unsigned* __restrict__ packed,
        const int* __restrict__ bcnt, unsigned short* __restrict__ perm,
        int* __restrict__ cnt, int* __restrict__ row_start) {
    __shared__ unsigned recs[BCAP];       // 24KB
    __shared__ unsigned short outs[PCAP]; // 12KB
    __shared__ int cntL[256];
    __shared__ int ws[4];
    __shared__ int totS;
    int b = blockIdx.x;
    int m = bcnt[b];
    if (m > BCAP) m = BCAP;
    int t = threadIdx.x;
    cntL[t] = 0;
    __syncthreads();
    int lo = b * BCAP;
    for (int i = t; i < m; i += 256) {
        unsigned r = packed[lo + i];
        recs[i] = r;
        atomicAdd(&cntL[(r >> 16) & 255], 1);
    }
    __syncthreads();
    int lane = t & 63, wave = t >> 6;
    int orig = cntL[t];
    int pc = (orig + 7) & ~7;            // padded per-node degree
    int v = pc;
    for (int o = 1; o < 64; o <<= 1) { int u = __shfl_up(v, o); if (lane >= o) v += u; }
    if (lane == 63) ws[wave] = v;
    __syncthreads();
    int off = 0;
    for (int w = 0; w < wave; ++w) off += ws[w];
    int st = v + off - pc;               // exclusive scan of padded degrees
    int node = b * 256 + t;
    if (node < NN) { cnt[node] = orig; row_start[node] = b * PCAP + st; }
    if (t == 255) totS = st + pc;
    __syncthreads();
    cntL[t] = st;
    __syncthreads();
    for (int i = t; i < m; i += 256) {
        unsigned r = recs[i];
        int pos = atomicAdd(&cntL[(r >> 16) & 255], 1);
        outs[pos] = (unsigned short)(r & 0xFFFFu);
    }
    // pad fill: disjoint from scatter's target region, no barrier needed
    for (int i = st + orig; i < st + pc; ++i) outs[i] = (unsigned short)NN;
    __syncthreads();
    int totp = totS;
    for (int i = t; i < totp; i += 256)
        perm[b * PCAP + i] = outs[i];
}

// ---------------- aggregate (mean over padded CSR, hi-plane only) ----------
// 1 node/wave. lane = (eg = lane>>4: edge group, cl = lane&15: 16B col chunk).
// One uint4 wave-load covers FOUR 256B rows. eg-reduce = shfl_xor 16, 32.
__global__ __launch_bounds__(256) void k_aggregate(const unsigned short* __restrict__ hhi,
        const int* __restrict__ row_start, const int* __restrict__ cnt,
        const unsigned short* __restrict__ perm,
        unsigned short* __restrict__ shi) {
    int wave = __builtin_amdgcn_readfirstlane(threadIdx.x >> 6);
    int lane = threadIdx.x & 63;
    int node = blockIdx.x * 4 + wave;
    if (node >= NN) return;
    int deg = cnt[node];
    int start = row_start[node];              // multiple of 8 -> 16B aligned
    int eg = lane >> 4;
    int hsh = (eg & 1) << 4;                  // ushort half within u32
    bool egHi = (eg & 2) != 0;                // which u32 of the pair
    int c16 = (lane & 15) << 4;               // byte offset of uint4 in row
    const char* base = (const char*)hhi;      // row stride 256B
    float a0=0.f,a1=0.f,a2=0.f,a3=0.f,a4=0.f,a5=0.f,a6=0.f,a7=0.f;
#define ACC8(q) { a0 += __uint_as_float((q).x << 16); a1 += __uint_as_float((q).x & 0xFFFF0000u); \
                  a2 += __uint_as_float((q).y << 16); a3 += __uint_as_float((q).y & 0xFFFF0000u); \
                  a4 += __uint_as_float((q).z << 16); a5 += __uint_as_float((q).z & 0xFFFF0000u); \
                  a6 += __uint_as_float((q).w << 16); a7 += __uint_as_float((q).w & 0xFFFF0000u); }
#define GATH(w) (*(const uint4*)(base + ((size_t)(((w) >> hsh) & 0xFFFFu) << 8) + c16))
    int pdeg = (deg + 7) & ~7;
    const uint4* pp = (const uint4*)(perm + start);
    int j = 0;
    for (; j + 16 <= pdeg; j += 16) {
        uint4 P0 = pp[0], P1 = pp[1]; pp += 2;
        unsigned w0 = egHi ? P0.y : P0.x;     // edges j+0+eg
        unsigned w1 = egHi ? P0.w : P0.z;     // edges j+4+eg
        unsigned w2 = egHi ? P1.y : P1.x;     // edges j+8+eg
        unsigned w3 = egHi ? P1.w : P1.z;     // edges j+12+eg
        uint4 q0 = GATH(w0);
        uint4 q1 = GATH(w1);
        uint4 q2 = GATH(w2);
        uint4 q3 = GATH(w3);
        ACC8(q0); ACC8(q1); ACC8(q2); ACC8(q3);
    }
    if (j < pdeg) {                           // exactly one 8-edge step
        uint4 P0 = *pp;
        unsigned w0 = egHi ? P0.y : P0.x;
        unsigned w1 = egHi ? P0.w : P0.z;
        uint4 q0 = GATH(w0);
        uint4 q1 = GATH(w1);
        ACC8(q0); ACC8(q1);
    }
#undef GATH
#undef ACC8
    // reduce across the 4 edge groups (^16 flips eg bit0, ^32 flips bit1)
    a0 += __shfl_xor(a0, 16); a1 += __shfl_xor(a1, 16);
    a2 += __shfl_xor(a2, 16); a3 += __shfl_xor(a3, 16);
    a4 += __shfl_xor(a4, 16); a5 += __shfl_xor(a5, 16);
    a6 += __shfl_xor(a6, 16); a7 += __shfl_xor(a7, 16);
    a0 += __shfl_xor(a0, 32); a1 += __shfl_xor(a1, 32);
    a2 += __shfl_xor(a2, 32); a3 += __shfl_xor(a3, 32);
    a4 += __shfl_xor(a4, 32); a5 += __shfl_xor(a5, 32);
    a6 += __shfl_xor(a6, 32); a7 += __shfl_xor(a7, 32);
    float inv = 1.0f / (float)(deg > 1 ? deg : 1);
    if (eg == 0) {
        uint4 o;
        o.x = (unsigned)bf16_rne(a0 * inv) | ((unsigned)bf16_rne(a1 * inv) << 16);
        o.y = (unsigned)bf16_rne(a2 * inv) | ((unsigned)bf16_rne(a3 * inv) << 16);
        o.z = (unsigned)bf16_rne(a4 * inv) | ((unsigned)bf16_rne(a5 * inv) << 16);
        o.w = (unsigned)bf16_rne(a6 * inv) | ((unsigned)bf16_rne(a7 * inv) << 16);
        ((uint4*)shi)[(size_t)node * 16 + (lane & 15)] = o;
    }
}

// ---------------- weight-stationary MFMA GEMM (pipelined grid-stride) ------
// out[n][c] = relu( bias[c] + sum_k [S|H][n][k] W[c][k] )
// A = {s_hi (mean, bf16), h_hi+h_lo (x, split)}. 12 dwordx4 A loads/tile,
// double-buffered across the grid-stride loop (prefetch t+512 before MFMA(t)).
#define GEMM_PROLOG \
    int wave = __builtin_amdgcn_readfirstlane(threadIdx.x >> 6); \
    int lane = threadIdx.x & 63; \
    int row = lane & 15; \
    int kb = lane >> 4; \
    int ct0 = wave * 2; \
    bf16x8 bh[2][8], bl[2][8]; \
    _Pragma("unroll") \
    for (int c = 0; c < 2; ++c) \
        _Pragma("unroll") \
        for (int kc = 0; kc < 8; ++kc) { \
            size_t widx = (size_t)((ct0 + c) * 16 + row) * 256 + kc * 32 + kb * 8; \
            bh[c][kc] = *(const bf16x8*)(Whi + widx); \
            bl[c][kc] = *(const bf16x8*)(Wlo + widx); \
        } \
    float b0 = bias[ct0 * 16 + row]; \
    float b1 = bias[ct0 * 16 + 16 + row];

#define LOADT(AS, AH, AL, t) { \
        size_t rb = (size_t)((t) * 16 + row) * 128 + kb * 8; \
        _Pragma("unroll") \
        for (int kc = 0; kc < 4; ++kc) { \
            AS[kc] = *(const bf16x8*)(Ash + rb + kc * 32); \
            AH[kc] = *(const bf16x8*)(Ahh + rb + kc * 32); \
            AL[kc] = *(const bf16x8*)(Ahl + rb + kc * 32); \
        } }

#define MFMA40(AS, AH, AL) \
        f32x4 acc0 = {0.f, 0.f, 0.f, 0.f}; \
        f32x4 acc1 = {0.f, 0.f, 0.f, 0.f}; \
        _Pragma("unroll") \
        for (int kc = 0; kc < 4; ++kc) { \
            acc0 = __builtin_amdgcn_mfma_f32_16x16x32_bf16(AS[kc], bh[0][kc], acc0, 0, 0, 0); \
            acc0 = __builtin_amdgcn_mfma_f32_16x16x32_bf16(AS[kc], bl[0][kc], acc0, 0, 0, 0); \
            acc1 = __builtin_amdgcn_mfma_f32_16x16x32_bf16(AS[kc], bh[1][kc], acc1, 0, 0, 0); \
            acc1 = __builtin_amdgcn_mfma_f32_16x16x32_bf16(AS[kc], bl[1][kc], acc1, 0, 0, 0); \
        } \
        _Pragma("unroll") \
        for (int kc = 0; kc < 4; ++kc) { \
            acc0 = __builtin_amdgcn_mfma_f32_16x16x32_bf16(AH[kc], bh[0][4 + kc], acc0, 0, 0, 0); \
            acc0 = __builtin_amdgcn_mfma_f32_16x16x32_bf16(AL[kc], bh[0][4 + kc], acc0, 0, 0, 0); \
            acc0 = __builtin_amdgcn_mfma_f32_16x16x32_bf16(AH[kc], bl[0][4 + kc], acc0, 0, 0, 0); \
            acc1 = __builtin_amdgcn_mfma_f32_16x16x32_bf16(AH[kc], bh[1][4 + kc], acc1, 0, 0, 0); \
            acc1 = __builtin_amdgcn_mfma_f32_16x16x32_bf16(AL[kc], bh[1][4 + kc], acc1, 0, 0, 0); \
            acc1 = __builtin_amdgcn_mfma_f32_16x16x32_bf16(AH[kc], bl[1][4 + kc], acc1, 0, 0, 0); \
        }

__global__ __launch_bounds__(256, 2) void k_gemm_ws(
        const unsigned short* __restrict__ Ash,
        const unsigned short* __restrict__ Ahh, const unsigned short* __restrict__ Ahl,
        const unsigned short* __restrict__ Whi, const unsigned short* __restrict__ Wlo,
        const float* __restrict__ bias,
        unsigned short* __restrict__ Ohi, unsigned short* __restrict__ Olo) {
    GEMM_PROLOG
#define STEP(AS, AH, AL, t) { \
        MFMA40(AS, AH, AL) \
        __syncthreads();   /* all waves' reads of tile t precede its writes */ \
        int cb0 = ct0 * 16 + row; \
        _Pragma("unroll") \
        for (int r = 0; r < 4; ++r) { \
            size_t ro = (size_t)((t) * 16 + kb * 4 + r) * 128; \
            unsigned p0 = pack_split(fmaxf(acc0[r] + b0, 0.f)); \
            unsigned p1 = pack_split(fmaxf(acc1[r] + b1, 0.f)); \
            Ohi[ro + cb0]      = (unsigned short)(p0 >> 16); \
            Olo[ro + cb0]      = (unsigned short)(p0 & 0xFFFFu); \
            Ohi[ro + cb0 + 16] = (unsigned short)(p1 >> 16); \
            Olo[ro + cb0 + 16] = (unsigned short)(p1 & 0xFFFFu); \
        } }
    bf16x8 sA[4], hA[4], lA[4], sB[4], hB[4], lB[4];
    int t = blockIdx.x;
    LOADT(sA, hA, lA, t)
    int tn = t + GGRID;
    for (;;) {
        if (tn < NTILE) LOADT(sB, hB, lB, tn)
        STEP(sA, hA, lA, t)
        if (tn >= NTILE) break;
        t = tn; tn += GGRID;
        if (tn < NTILE) LOADT(sA, hA, lA, tn)
        STEP(sB, hB, lB, t)
        if (tn >= NTILE) break;
        t = tn; tn += GGRID;
    }
#undef STEP
}

// layer-2 variant: head fused — out[n] += sum_c relu(h3[n][c]) * Wf[c]
__global__ __launch_bounds__(256, 2) void k_gemm_head(
        const unsigned short* __restrict__ Ash,
        const unsigned short* __restrict__ Ahh, const unsigned short* __restrict__ Ahl,
        const unsigned short* __restrict__ Whi, const unsigned short* __restrict__ Wlo,
        const float* __restrict__ bias, const float* __restrict__ Wf,
        float* __restrict__ out) {
    GEMM_PROLOG
    float w0 = Wf[ct0 * 16 + row];
    float w1 = Wf[ct0 * 16 + 16 + row];
#define HSTEP(AS, AH, AL, t) { \
        MFMA40(AS, AH, AL) \
        float part[4]; \
        _Pragma("unroll") \
        for (int r = 0; r < 4; ++r) \
            part[r] = fmaxf(acc0[r] + b0, 0.f) * w0 + fmaxf(acc1[r] + b1, 0.f) * w1; \
        _Pragma("unroll") \
        for (int o = 1; o < 16; o <<= 1) { \
            _Pragma("unroll") \
            for (int r = 0; r < 4; ++r) part[r] += __shfl_xor(part[r], o); \
        } \
        if (row == 0) { \
            _Pragma("unroll") \
            for (int r = 0; r < 4; ++r) atomicAdd(&out[(t) * 16 + kb * 4 + r], part[r]); \
        } }
    bf16x8 sA[4], hA[4], lA[4], sB[4], hB[4], lB[4];
    int t = blockIdx.x;
    LOADT(sA, hA, lA, t)
    int tn = t + GGRID;
    for (;;) {
        if (tn < NTILE) LOADT(sB, hB, lB, tn)
        HSTEP(sA, hA, lA, t)
        if (tn >= NTILE) break;
        t = tn; tn += GGRID;
        if (tn < NTILE) LOADT(sA, hA, lA, tn)
        HSTEP(sB, hB, lB, t)
        if (tn >= NTILE) break;
        t = tn; tn += GGRID;
    }
#undef HSTEP
}

extern "C" void kernel_launch(void* const* d_in, const int* in_sizes, int n_in,
                              void* d_out, int out_size, void* d_ws, size_t ws_size,
                              hipStream_t stream) {
    const float* x   = (const float*)d_in[0];
    const int*   ei  = (const int*)d_in[1];
    const float* Wl0 = (const float*)d_in[2];
    const float* bl0 = (const float*)d_in[3];
    const float* Wr0 = (const float*)d_in[4];
    const float* Wl1 = (const float*)d_in[5];
    const float* bl1 = (const float*)d_in[6];
    const float* Wr1 = (const float*)d_in[7];
    const float* Wl2 = (const float*)d_in[8];
    const float* bl2 = (const float*)d_in[9];
    const float* Wr2 = (const float*)d_in[10];
    const float* Wf  = (const float*)d_in[11];
    const float* bf  = (const float*)d_in[12];
    float* out = (float*)d_out;

    char* p = (char*)d_ws;
    auto alloc = [&](size_t n) { void* r = (void*)p; p += (n + 255) & ~(size_t)255; return r; };
    int*            bcnt      = (int*)alloc(256 * 4);
    int*            cnt       = (int*)alloc((size_t)NN * 4);
    int*            row_start = (int*)alloc((size_t)NN * 4);
    unsigned short* perm      = (unsigned short*)alloc((size_t)NBUCK * PCAP * 2);
    unsigned short* s_hi      = (unsigned short*)alloc((size_t)(NN + 1) * 128 * 2);
    unsigned short* h_hi      = (unsigned short*)alloc((size_t)(NN + 1) * 128 * 2);
    unsigned short* h_lo      = (unsigned short*)alloc((size_t)(NN + 1) * 128 * 2);
    unsigned short* whi       = (unsigned short*)alloc((size_t)3 * 128 * 256 * 2);
    unsigned short* wlo       = (unsigned short*)alloc((size_t)3 * 128 * 256 * 2);
    unsigned*       packed    = (unsigned*)s_hi;  // 4.8MB < 12.8MB; consumed
                                                  // by bucket_csr before agg

    dim3 b256(256);
    // pack x + weights + all init (out bias, bcnt, sentinel) — precedes build
    k_packinit<<<dim3(XBLK + 384), b256, 0, stream>>>(
        x, h_hi, h_lo, out, bf, bcnt,
        Wl0, Wr0, Wl1, Wr1, Wl2, Wr2, whi, wlo);
    // CSR build: 2 kernels
    k_build_buckets<<<dim3(NBLK), b256, 0, stream>>>(ei, bcnt, packed);
    k_bucket_csr<<<dim3(NBUCK), b256, 0, stream>>>(packed, bcnt, perm, cnt, row_start);

    dim3 gAgg((NN + 3) / 4);    // 1 node/wave, 4 per block
    dim3 gGemm(GGRID);          // 2 blocks/CU; grid-stride over 3125 tiles

    // layer 0
    k_aggregate<<<gAgg, b256, 0, stream>>>(h_hi, row_start, cnt, perm, s_hi);
    k_gemm_ws<<<gGemm, b256, 0, stream>>>(s_hi, h_hi, h_lo,
                                          whi + 0 * 32768, wlo + 0 * 32768, bl0, h_hi, h_lo);
    // layer 1 (in place)
    k_aggregate<<<gAgg, b256, 0, stream>>>(h_hi, row_start, cnt, perm, s_hi);
    k_gemm_ws<<<gGemm, b256, 0, stream>>>(s_hi, h_hi, h_lo,
                                          whi + 1 * 32768, wlo + 1 * 32768, bl1, h_hi, h_lo);
    // layer 2 + fused head
    k_aggregate<<<gAgg, b256, 0, stream>>>(h_hi, row_start, cnt, perm, s_hi);
    k_gemm_head<<<gGemm, b256, 0, stream>>>(s_hi, h_hi, h_lo,
                                            whi + 2 * 32768, wlo + 2 * 32768, bl2, Wf, out);
}